// Round 6
// baseline (1080.497 us; speedup 1.0000x reference)
//
#include <hip/hip_runtime.h>

typedef short bf16x8 __attribute__((ext_vector_type(8)));
typedef float f32x4 __attribute__((ext_vector_type(4)));
typedef unsigned short u16;

#define GLDS16(g, l) __builtin_amdgcn_global_load_lds( \
    (const __attribute__((address_space(1))) void*)(g), \
    (__attribute__((address_space(3))) void*)(l), 16, 0, 0)

__device__ __forceinline__ u16 f2b(float f) {
  unsigned u = __float_as_uint(f);
  u += 0x7fffu + ((u >> 16) & 1u);
  return (u16)(u >> 16);
}

// ---------------- weight transpose + bf16 convert: w[K][N] -> wt[N][K] ----------------
__global__ __launch_bounds__(256)
void transpose_bf16(const float* __restrict__ w, u16* __restrict__ wt, int K, int N) {
  __shared__ float tile[32][33];
  const int n0 = blockIdx.x * 32, k0 = blockIdx.y * 32;
  const int tx = threadIdx.x & 31, ty = threadIdx.x >> 5;   // 32 x 8
#pragma unroll
  for (int i = 0; i < 4; ++i)
    tile[ty + i * 8][tx] = w[(size_t)(k0 + ty + i * 8) * N + n0 + tx];
  __syncthreads();
#pragma unroll
  for (int i = 0; i < 4; ++i)
    wt[(size_t)(n0 + ty + i * 8) * K + k0 + tx] = f2b(tile[tx][ty + i * 8]);
}

// ---------------- layernorm (optional gather-permute) -> bf16 row ----------------
__global__ __launch_bounds__(256)
void ln_rows(const float* __restrict__ src, const float* __restrict__ gam,
             const float* __restrict__ bet, const int* __restrict__ perm,
             u16* __restrict__ dst) {
  const int orow = blockIdx.x;                 // output row, 0..16383
  const int b = orow >> 12, j = orow & 4095;
  const int srow = perm ? ((b << 12) + perm[j]) : orow;
  const float4 v = ((const float4*)(src + (size_t)srow * 1024))[threadIdx.x];
  float s = v.x + v.y + v.z + v.w;
  float s2 = v.x * v.x + v.y * v.y + v.z * v.z + v.w * v.w;
#pragma unroll
  for (int d = 1; d < 64; d <<= 1) { s += __shfl_xor(s, d); s2 += __shfl_xor(s2, d); }
  __shared__ float rs[4], rs2[4];
  const int wave = threadIdx.x >> 6, lane = threadIdx.x & 63;
  if (lane == 0) { rs[wave] = s; rs2[wave] = s2; }
  __syncthreads();
  s = rs[0] + rs[1] + rs[2] + rs[3];
  s2 = rs2[0] + rs2[1] + rs2[2] + rs2[3];
  const float mu = s * (1.f / 1024.f);
  const float var = s2 * (1.f / 1024.f) - mu * mu;
  const float rstd = rsqrtf(var + 1e-5f);
  const int c = threadIdx.x * 4;
  const float4 gg = *(const float4*)(gam + c);
  const float4 bb = *(const float4*)(bet + c);
  const u16 o0 = f2b((v.x - mu) * rstd * gg.x + bb.x);
  const u16 o1 = f2b((v.y - mu) * rstd * gg.y + bb.y);
  const u16 o2 = f2b((v.z - mu) * rstd * gg.z + bb.z);
  const u16 o3 = f2b((v.w - mu) * rstd * gg.w + bb.w);
  const unsigned lo = (unsigned)o0 | ((unsigned)o1 << 16);
  const unsigned hi = (unsigned)o2 | ((unsigned)o3 << 16);
  *(uint2*)(dst + (size_t)orow * 1024 + c) = make_uint2(lo, hi);
}

// ---------------- 256x256 GEMM, REGISTER-STAGED pipeline (no global_load_lds) ----------------
// 8 waves (2M x 4N), BK=64, double-buffered 128 KiB LDS, XOR-swizzled ds_write/ds_read.
// Per tile: ph0 {ds_read aLo+bLo, vmcnt(0), ds_write staged t+1, bar, lgkm0, MFMA LL, bar}
//           ph1 {ds_read bHi, issue B-loads t+2, bar, lgkm0, MFMA LH, bar}
//           ph2 {ds_read aHi, issue A-loads t+2, bar, lgkm0, MFMA HL, bar}
//           ph3 {MFMA HH, bar}
// Loads for tile t+1 are issued a full tile before their vmcnt(0) -> wait is free.
// EPI 0: bf16 store; 1: GELU+bf16; 2: perm-scatter + resid, fp32; 3: resid, fp32
template <int EPI>
__global__ __launch_bounds__(512, 2)
void gemm256(const u16* __restrict__ A, const u16* __restrict__ Bt,
             const float* __restrict__ bias, void* __restrict__ Cout,
             const float* __restrict__ resid, const int* __restrict__ perm,
             int M, int Nn, int K) {
  __shared__ u16 sm[65536];                 // 128 KiB: [buf0|buf1], each {A 32K, B 32K}
  char* const smc = (char*)sm;
  const int tid = threadIdx.x;
  const int w = tid >> 6, lane = tid & 63;
  const int lr = lane & 15, lg = lane >> 4;
  const int wm = w >> 2, wn = w & 3;

  // bijective XCD swizzle (all our grids are %8==0)
  int wg = blockIdx.x;
  const int nwg = gridDim.x;
  if ((nwg & 7) == 0) { const int per = nwg >> 3; wg = (wg & 7) * per + (wg >> 3); }
  const int gx = M >> 8;
  const int m0 = (wg % gx) << 8, n0 = (wg / gx) << 8;

  // staging: linear global reads -> VGPR -> swizzled ds_write.
  // LDS[row][slot16] holds global col-slot (slot16 ^ (row&7)).
  const int srow = tid >> 3;                                   // 0..63
  const int lin8 = (tid & 7) << 3;                             // linear col (elements)
  const u16* gA = A + (size_t)(m0 + srow) * K + lin8;
  const u16* gB = Bt + (size_t)(n0 + srow) * K + lin8;
  const int wslot = ((tid & 7) ^ (srow & 7)) << 4;             // swizzled byte slot

  // read-side constants (unchanged swizzle algebra)
  const int slot0 = (lg ^ (lr & 7)) << 4;
  const int aRow = (wm * 128 + lr) * 128;
  const int bRow = (wn * 64 + lr) * 128 + 32768;

  const int NT = K >> 6;

  uint4 astg[4], bstg[4];

#define LOADA_(k0) do { _Pragma("unroll") for (int i = 0; i < 4; ++i) \
    astg[i] = *(const uint4*)(gA + (size_t)(64 * i) * K + (k0)); } while (0)
#define LOADB_(k0) do { _Pragma("unroll") for (int i = 0; i < 4; ++i) \
    bstg[i] = *(const uint4*)(gB + (size_t)(64 * i) * K + (k0)); } while (0)
#define WRITEAB_(d) do { char* base_ = smc + (d) * 65536; \
    _Pragma("unroll") for (int i = 0; i < 4; ++i) { \
      *(uint4*)(base_ + (srow + 64 * i) * 128 + wslot) = astg[i]; \
      *(uint4*)(base_ + 32768 + (srow + 64 * i) * 128 + wslot) = bstg[i]; } } while (0)

  // fragment registers: a[] reused for Lo (ph0-1) then Hi (ph2-3)
  bf16x8 a[8], bLo[4], bHi[4];

#define R_ALO(P) do { _Pragma("unroll") for (int mf = 0; mf < 4; ++mf) \
    _Pragma("unroll") for (int kk = 0; kk < 2; ++kk) \
      a[mf * 2 + kk] = *(const bf16x8*)((P) + mf * 2048 + (slot0 ^ (kk << 6))); } while (0)
#define R_AHI(P) do { _Pragma("unroll") for (int mf = 0; mf < 4; ++mf) \
    _Pragma("unroll") for (int kk = 0; kk < 2; ++kk) \
      a[mf * 2 + kk] = *(const bf16x8*)((P) + (4 + mf) * 2048 + (slot0 ^ (kk << 6))); } while (0)
#define R_BLO(P) do { _Pragma("unroll") for (int nf = 0; nf < 2; ++nf) \
    _Pragma("unroll") for (int kk = 0; kk < 2; ++kk) \
      bLo[nf * 2 + kk] = *(const bf16x8*)((P) + nf * 2048 + (slot0 ^ (kk << 6))); } while (0)
#define R_BHI(P) do { _Pragma("unroll") for (int nf = 0; nf < 2; ++nf) \
    _Pragma("unroll") for (int kk = 0; kk < 2; ++kk) \
      bHi[nf * 2 + kk] = *(const bf16x8*)((P) + (2 + nf) * 2048 + (slot0 ^ (kk << 6))); } while (0)

#define QUAD_(BARR, MB, NB) do { _Pragma("unroll") for (int mf = 0; mf < 4; ++mf) \
    _Pragma("unroll") for (int nf = 0; nf < 2; ++nf) \
    _Pragma("unroll") for (int kk = 0; kk < 2; ++kk) \
      acc[(MB) * 4 + mf][(NB) * 2 + nf] = __builtin_amdgcn_mfma_f32_16x16x32_bf16( \
          a[mf * 2 + kk], BARR[nf * 2 + kk], acc[(MB) * 4 + mf][(NB) * 2 + nf], 0, 0, 0); } while (0)

#define LGKM0SB_() do { asm volatile("s_waitcnt lgkmcnt(0)" ::: "memory"); \
                        __builtin_amdgcn_sched_barrier(0); } while (0)

  // prologue: tile0 -> regs -> buf0; issue tile1 loads
  LOADB_(0); LOADA_(0);
  asm volatile("s_waitcnt vmcnt(0)" ::: "memory");
  WRITEAB_(0);
  if (NT > 1) { LOADB_(64); LOADA_(64); }
  asm volatile("s_waitcnt lgkmcnt(0)" ::: "memory");
  __builtin_amdgcn_s_barrier();

  f32x4 acc[8][4] = {};

  for (int t = 0; t < NT; ++t) {
    const int c = t & 1;
    const char* cA = smc + c * 65536 + aRow;
    const char* cB = smc + c * 65536 + bRow;

    // ---- phase 0: read aLo+bLo; land t+1 loads; ds_write t+1 -> other buf; MFMA LL
    R_ALO(cA); R_BLO(cB);
    if (t + 1 < NT) {
      asm volatile("s_waitcnt vmcnt(0)" ::: "memory");
      WRITEAB_(c ^ 1);
    }
    __builtin_amdgcn_s_barrier();
    LGKM0SB_();
    __builtin_amdgcn_s_setprio(1);
    QUAD_(bLo, 0, 0);
    __builtin_amdgcn_s_setprio(0);
    __builtin_amdgcn_s_barrier();

    // ---- phase 1: read bHi; issue B loads (t+2); MFMA LH
    R_BHI(cB);
    if (t + 2 < NT) LOADB_((t + 2) << 6);
    __builtin_amdgcn_s_barrier();
    LGKM0SB_();
    __builtin_amdgcn_s_setprio(1);
    QUAD_(bHi, 0, 1);
    __builtin_amdgcn_s_setprio(0);
    __builtin_amdgcn_s_barrier();

    // ---- phase 2: read aHi; issue A loads (t+2); MFMA HL
    R_AHI(cA);
    if (t + 2 < NT) LOADA_((t + 2) << 6);
    __builtin_amdgcn_s_barrier();
    LGKM0SB_();
    __builtin_amdgcn_s_setprio(1);
    QUAD_(bLo, 1, 0);
    __builtin_amdgcn_s_setprio(0);
    __builtin_amdgcn_s_barrier();

    // ---- phase 3: MFMA HH
    __builtin_amdgcn_sched_barrier(0);
    __builtin_amdgcn_s_setprio(1);
    QUAD_(bHi, 1, 1);
    __builtin_amdgcn_s_setprio(0);
    __builtin_amdgcn_s_barrier();
  }
#undef LOADA_
#undef LOADB_
#undef WRITEAB_
#undef R_ALO
#undef R_AHI
#undef R_BLO
#undef R_BHI
#undef QUAD_
#undef LGKM0SB_

  // epilogue
#pragma unroll
  for (int mf = 0; mf < 8; ++mf) {
#pragma unroll
    for (int nf = 0; nf < 4; ++nf) {
      const int col = n0 + wn * 64 + nf * 16 + lr;
      const float bia = bias[col];
#pragma unroll
      for (int r = 0; r < 4; ++r) {
        const int row = m0 + wm * 128 + mf * 16 + lg * 4 + r;
        float v = acc[mf][nf][r] + bia;
        if (EPI == 0) {
          ((u16*)Cout)[(size_t)row * Nn + col] = f2b(v);
        } else if (EPI == 1) {
          v = 0.5f * v * (1.f + erff(v * 0.70710678118654752f));
          ((u16*)Cout)[(size_t)row * Nn + col] = f2b(v);
        } else if (EPI == 2) {
          const int b = row >> 12, j = row & 4095;
          const size_t di = ((size_t)((b << 12) + perm[j])) * 1024 + col;
          ((float*)Cout)[di] = resid[di] + v;
        } else {
          const size_t di = (size_t)row * 1024 + col;
          ((float*)Cout)[di] = resid[di] + v;
        }
      }
    }
  }
}

// ---------------- dilated attention: 1 block per (b, seg, head) ----------------
__global__ __launch_bounds__(256, 2)
void attn_kernel(const u16* __restrict__ qkv, u16* __restrict__ outp) {
  const int blk = blockIdx.x;
  const int h = blk & 15, g = (blk >> 4) & 15, b = blk >> 8;
  const int tid = threadIdx.x, wave = tid >> 6, lane = tid & 63;
  const int lr = lane & 15, lg = lane >> 4;
  const int par = h & 1;

  __shared__ u16 lQ[128 * 64];
  __shared__ u16 lK[128 * 64];
  __shared__ u16 lVt[64 * 128];      // [dh][key]
  __shared__ u16 lP[4][32 * 128];    // per-wave P

  const size_t rbase = (size_t)((b << 12) + (g << 8) + par);

#pragma unroll
  for (int i = 0; i < 4; ++i) {
    const int ou = i * 4096 + wave * 1024;
    const int o = ou + lane * 16;
    const int j = o >> 7, cb = o & 127;
    const u16* gq = qkv + (rbase + 2 * j) * 3072 + h * 64 + (cb >> 1);
    GLDS16(gq, (char*)lQ + ou);
    GLDS16(gq + 1024, (char*)lK + ou);
  }
#pragma unroll
  for (int i = 0; i < 4; ++i) {
    const int c = tid + i * 256;
    const int j = c >> 3, dc = c & 7;
    const uint4 vv = *(const uint4*)(qkv + (rbase + 2 * j) * 3072 + 2048 + h * 64 + dc * 8);
    const u16* pv = (const u16*)&vv;
#pragma unroll
    for (int e = 0; e < 8; ++e) lVt[(dc * 8 + e) * 128 + j] = pv[e];
  }
  __syncthreads();

  f32x4 sacc[2][8] = {};
#pragma unroll
  for (int kk = 0; kk < 2; ++kk) {
    bf16x8 aq[2], bk[8];
#pragma unroll
    for (int mf = 0; mf < 2; ++mf)
      aq[mf] = *(const bf16x8*)&lQ[(wave * 32 + mf * 16 + lr) * 64 + kk * 32 + lg * 8];
#pragma unroll
    for (int nf = 0; nf < 8; ++nf)
      bk[nf] = *(const bf16x8*)&lK[(nf * 16 + lr) * 64 + kk * 32 + lg * 8];
#pragma unroll
    for (int mf = 0; mf < 2; ++mf)
#pragma unroll
      for (int nf = 0; nf < 8; ++nf)
        sacc[mf][nf] = __builtin_amdgcn_mfma_f32_16x16x32_bf16(aq[mf], bk[nf], sacc[mf][nf], 0, 0, 0);
  }

#pragma unroll
  for (int mf = 0; mf < 2; ++mf) {
#pragma unroll
    for (int r = 0; r < 4; ++r) {
      float mx = -3e38f;
#pragma unroll
      for (int nf = 0; nf < 8; ++nf) mx = fmaxf(mx, sacc[mf][nf][r]);
#pragma unroll
      for (int d = 1; d < 16; d <<= 1) mx = fmaxf(mx, __shfl_xor(mx, d));
      float pv[8];
      float sum = 0.f;
#pragma unroll
      for (int nf = 0; nf < 8; ++nf) {
        pv[nf] = __expf((sacc[mf][nf][r] - mx) * 0.125f);
        sum += pv[nf];
      }
#pragma unroll
      for (int d = 1; d < 16; d <<= 1) sum += __shfl_xor(sum, d);
      const float inv = 1.f / sum;
      const int rrow = mf * 16 + lg * 4 + r;
#pragma unroll
      for (int nf = 0; nf < 8; ++nf)
        lP[wave][rrow * 128 + nf * 16 + lr] = f2b(pv[nf] * inv);
    }
  }
  __syncthreads();

  f32x4 oacc[2][4] = {};
#pragma unroll
  for (int kk = 0; kk < 4; ++kk) {
    bf16x8 ap[2], bv[4];
#pragma unroll
    for (int mf = 0; mf < 2; ++mf)
      ap[mf] = *(const bf16x8*)&lP[wave][(mf * 16 + lr) * 128 + kk * 32 + lg * 8];
#pragma unroll
    for (int nf = 0; nf < 4; ++nf)
      bv[nf] = *(const bf16x8*)&lVt[(nf * 16 + lr) * 128 + kk * 32 + lg * 8];
#pragma unroll
    for (int mf = 0; mf < 2; ++mf)
#pragma unroll
      for (int nf = 0; nf < 4; ++nf)
        oacc[mf][nf] = __builtin_amdgcn_mfma_f32_16x16x32_bf16(ap[mf], bv[nf], oacc[mf][nf], 0, 0, 0);
  }

  u16* obase = outp + ((size_t)((b << 12) + (g << 8))) * 1024 + h * 64;
#pragma unroll
  for (int mf = 0; mf < 2; ++mf)
#pragma unroll
    for (int nf = 0; nf < 4; ++nf)
#pragma unroll
      for (int r = 0; r < 4; ++r) {
        const int jq = wave * 32 + mf * 16 + lg * 4 + r;
        obase[(size_t)(par + 2 * jq) * 1024 + nf * 16 + lr] = f2b(oacc[mf][nf][r]);
      }
  const int jz = tid >> 1, hh = (tid & 1) * 32;
  u16* zp = obase + (size_t)((1 - par) + 2 * jz) * 1024 + hh;
  const uint4 z = make_uint4(0u, 0u, 0u, 0u);
#pragma unroll
  for (int i = 0; i < 4; ++i) ((uint4*)zp)[i] = z;
}

// ---------------- launch ----------------
extern "C" void kernel_launch(void* const* d_in, const int* in_sizes, int n_in,
                              void* d_out, int out_size, void* d_ws, size_t ws_size,
                              hipStream_t stream) {
  const float* x    = (const float*)d_in[0];
  const float* ln1g = (const float*)d_in[1];
  const float* ln1b = (const float*)d_in[2];
  const float* wqkv = (const float*)d_in[3];
  const float* bqkv = (const float*)d_in[4];
  const float* wo   = (const float*)d_in[5];
  const float* bo   = (const float*)d_in[6];
  const float* ln2g = (const float*)d_in[7];
  const float* ln2b = (const float*)d_in[8];
  const float* w1   = (const float*)d_in[9];
  const float* b1   = (const float*)d_in[10];
  const float* w2   = (const float*)d_in[11];
  const float* b2   = (const float*)d_in[12];
  const int*   perm = (const int*)d_in[13];
  float* out = (float*)d_out;
  char* ws = (char*)d_ws;

  u16*  r0    = (u16*)ws;                         // 32 MB: xp -> attn_out -> h2
  u16*  qkv   = (u16*)(ws + (32ull << 20));       // 96 MB
  u16*  a1    = (u16*)(ws + (32ull << 20));       // 128 MB (qkv dead by then)
  float* x2   = (float*)(ws + (160ull << 20));    // 64 MB
  u16*  wqkvT = (u16*)(ws + (224ull << 20));      // 6 MB
  u16*  woT   = (u16*)(ws + (230ull << 20));      // 2 MB
  u16*  w1T   = (u16*)(ws + (232ull << 20));      // 8 MB
  u16*  w2T   = (u16*)(ws + (240ull << 20));      // 8 MB

  transpose_bf16<<<dim3(3072 / 32, 1024 / 32), 256, 0, stream>>>(wqkv, wqkvT, 1024, 3072);
  transpose_bf16<<<dim3(1024 / 32, 1024 / 32), 256, 0, stream>>>(wo, woT, 1024, 1024);
  transpose_bf16<<<dim3(4096 / 32, 1024 / 32), 256, 0, stream>>>(w1, w1T, 1024, 4096);
  transpose_bf16<<<dim3(1024 / 32, 4096 / 32), 256, 0, stream>>>(w2, w2T, 4096, 1024);

  ln_rows<<<16384, 256, 0, stream>>>(x, ln1g, ln1b, perm, r0);                  // xp = LN1(x)[perm]
  gemm256<0><<<(16384 / 256) * (3072 / 256), 512, 0, stream>>>(r0, wqkvT, bqkv, qkv, nullptr, nullptr,
                                                               16384, 3072, 1024);
  attn_kernel<<<1024, 256, 0, stream>>>(qkv, r0);                               // attn_out
  gemm256<2><<<(16384 / 256) * (1024 / 256), 512, 0, stream>>>(r0, woT, bo, x2, x, perm,
                                                               16384, 1024, 1024);
  ln_rows<<<16384, 256, 0, stream>>>(x2, ln2g, ln2b, nullptr, r0);              // h2 = LN2(x2)
  gemm256<1><<<(16384 / 256) * (4096 / 256), 512, 0, stream>>>(r0, w1T, b1, a1, nullptr, nullptr,
                                                               16384, 4096, 1024);
  gemm256<3><<<(16384 / 256) * (1024 / 256), 512, 0, stream>>>(a1, w2T, b2, out, x2, nullptr,
                                                               16384, 1024, 4096);
}

// Round 7
// 617.479 us; speedup vs baseline: 1.7499x; 1.7499x over previous
//
#include <hip/hip_runtime.h>

typedef short bf16x8 __attribute__((ext_vector_type(8)));
typedef float f32x4 __attribute__((ext_vector_type(4)));
typedef unsigned short u16;

#define GLDS16(g, l) __builtin_amdgcn_global_load_lds( \
    (const __attribute__((address_space(1))) void*)(g), \
    (__attribute__((address_space(3))) void*)(l), 16, 0, 0)

// opaque-to-legalizer LDS read: no compiler-inserted vmcnt(0) ordering vs LDS-DMA
#define DSR_(dst, p) asm volatile("ds_read_b128 %0, %1" \
    : "=v"(dst) : "v"((const __attribute__((address_space(3))) void*)(p)))

__device__ __forceinline__ u16 f2b(float f) {
  unsigned u = __float_as_uint(f);
  u += 0x7fffu + ((u >> 16) & 1u);
  return (u16)(u >> 16);
}

// ---------------- weight transpose + bf16 convert: w[K][N] -> wt[N][K] ----------------
__global__ __launch_bounds__(256)
void transpose_bf16(const float* __restrict__ w, u16* __restrict__ wt, int K, int N) {
  __shared__ float tile[32][33];
  const int n0 = blockIdx.x * 32, k0 = blockIdx.y * 32;
  const int tx = threadIdx.x & 31, ty = threadIdx.x >> 5;   // 32 x 8
#pragma unroll
  for (int i = 0; i < 4; ++i)
    tile[ty + i * 8][tx] = w[(size_t)(k0 + ty + i * 8) * N + n0 + tx];
  __syncthreads();
#pragma unroll
  for (int i = 0; i < 4; ++i)
    wt[(size_t)(n0 + ty + i * 8) * K + k0 + tx] = f2b(tile[tx][ty + i * 8]);
}

// ---------------- layernorm (optional gather-permute) -> bf16 row ----------------
__global__ __launch_bounds__(256)
void ln_rows(const float* __restrict__ src, const float* __restrict__ gam,
             const float* __restrict__ bet, const int* __restrict__ perm,
             u16* __restrict__ dst) {
  const int orow = blockIdx.x;                 // output row, 0..16383
  const int b = orow >> 12, j = orow & 4095;
  const int srow = perm ? ((b << 12) + perm[j]) : orow;
  const float4 v = ((const float4*)(src + (size_t)srow * 1024))[threadIdx.x];
  float s = v.x + v.y + v.z + v.w;
  float s2 = v.x * v.x + v.y * v.y + v.z * v.z + v.w * v.w;
#pragma unroll
  for (int d = 1; d < 64; d <<= 1) { s += __shfl_xor(s, d); s2 += __shfl_xor(s2, d); }
  __shared__ float rs[4], rs2[4];
  const int wave = threadIdx.x >> 6, lane = threadIdx.x & 63;
  if (lane == 0) { rs[wave] = s; rs2[wave] = s2; }
  __syncthreads();
  s = rs[0] + rs[1] + rs[2] + rs[3];
  s2 = rs2[0] + rs2[1] + rs2[2] + rs2[3];
  const float mu = s * (1.f / 1024.f);
  const float var = s2 * (1.f / 1024.f) - mu * mu;
  const float rstd = rsqrtf(var + 1e-5f);
  const int c = threadIdx.x * 4;
  const float4 gg = *(const float4*)(gam + c);
  const float4 bb = *(const float4*)(bet + c);
  const u16 o0 = f2b((v.x - mu) * rstd * gg.x + bb.x);
  const u16 o1 = f2b((v.y - mu) * rstd * gg.y + bb.y);
  const u16 o2 = f2b((v.z - mu) * rstd * gg.z + bb.z);
  const u16 o3 = f2b((v.w - mu) * rstd * gg.w + bb.w);
  const unsigned lo = (unsigned)o0 | ((unsigned)o1 << 16);
  const unsigned hi = (unsigned)o2 | ((unsigned)o3 << 16);
  *(uint2*)(dst + (size_t)orow * 1024 + c) = make_uint2(lo, hi);
}

// ---------------- 256x256 GEMM, 8-phase, asm ds_read (legalizer-opaque) ----------------
// 8 waves (2M x 4N), BK=64, double-buffered 128 KiB LDS, st-swizzle, counted vmcnt(6).
// Stages: ph0 A-h1(t+1)->other buf; ph2 B-h0+B-h1(t+2)->this buf (B reads done at ph1);
// ph3 A-h0(t+2)->this buf (A reads done at ph2); vmcnt(6) at ph3.
// EPI 0: bf16 store; 1: GELU+bf16; 2: perm-scatter + resid, fp32; 3: resid, fp32
template <int EPI>
__global__ __launch_bounds__(512, 2)
void gemm256(const u16* __restrict__ A, const u16* __restrict__ Bt,
             const float* __restrict__ bias, void* __restrict__ Cout,
             const float* __restrict__ resid, const int* __restrict__ perm,
             int M, int Nn, int K) {
  __shared__ u16 sm[65536];                 // 128 KiB: [buf0|buf1], each {A 32K, B 32K}
  char* const smc = (char*)sm;
  const int tid = threadIdx.x;
  const int w = tid >> 6, lane = tid & 63;
  const int lr = lane & 15, lg = lane >> 4;
  const int wm = w >> 2, wn = w & 3;

  // bijective XCD swizzle (all our grids are %8==0)
  int wg = blockIdx.x;
  const int nwg = gridDim.x;
  if ((nwg & 7) == 0) { const int per = nwg >> 3; wg = (wg & 7) * per + (wg >> 3); }
  const int gx = M >> 8;
  const int m0 = (wg % gx) << 8, n0 = (wg / gx) << 8;

  // staging: LDS written linearly by global_load_lds; global source pre-swizzled
  // so ds_read with (col ^ ((row&7)<<4)) is correct.
  const int srow = tid >> 3;                                   // 0..63
  const int scol = ((tid & 7) ^ (srow & 7)) << 3;              // element col
  const size_t aSrc = (size_t)(m0 + srow) * K + scol;
  const size_t bSrc = (size_t)(n0 + srow) * K + scol;
  char* const lWav = smc + w * 1024;

  // read-side constants
  const int slot0 = (lg ^ (lr & 7)) << 4;                      // swizzled 16B slot
  const int aRow = (wm * 128 + lr) * 128;
  const int bRow = (wn * 64 + lr) * 128 + 32768;

  const int NT = K >> 6;

#define STAGE_(d, mat, h, k0) do { \
    const u16* gp = ((mat) ? Bt : A) + ((mat) ? bSrc : aSrc) + (size_t)(h) * 128 * K + (k0); \
    char* lp = lWav + (d) * 65536 + (mat) * 32768 + (h) * 16384; \
    GLDS16(gp, lp); GLDS16(gp + (size_t)64 * K, lp + 8192); } while (0)

  // fragment registers (consumed same-phase, after explicit lgkmcnt(0))
  bf16x8 aLo[8], aHi[8], bLo[4], bHi[4];

#define R_ALO(P) do { _Pragma("unroll") for (int mf = 0; mf < 4; ++mf) \
    _Pragma("unroll") for (int kk = 0; kk < 2; ++kk) \
      DSR_(aLo[mf * 2 + kk], (P) + mf * 2048 + (slot0 ^ (kk << 6))); } while (0)
#define R_AHI(P) do { _Pragma("unroll") for (int mf = 0; mf < 4; ++mf) \
    _Pragma("unroll") for (int kk = 0; kk < 2; ++kk) \
      DSR_(aHi[mf * 2 + kk], (P) + (4 + mf) * 2048 + (slot0 ^ (kk << 6))); } while (0)
#define R_BLO(P) do { _Pragma("unroll") for (int nf = 0; nf < 2; ++nf) \
    _Pragma("unroll") for (int kk = 0; kk < 2; ++kk) \
      DSR_(bLo[nf * 2 + kk], (P) + nf * 2048 + (slot0 ^ (kk << 6))); } while (0)
#define R_BHI(P) do { _Pragma("unroll") for (int nf = 0; nf < 2; ++nf) \
    _Pragma("unroll") for (int kk = 0; kk < 2; ++kk) \
      DSR_(bHi[nf * 2 + kk], (P) + (2 + nf) * 2048 + (slot0 ^ (kk << 6))); } while (0)

#define QUAD_(AARR, BARR, MB, NB) do { _Pragma("unroll") for (int mf = 0; mf < 4; ++mf) \
    _Pragma("unroll") for (int nf = 0; nf < 2; ++nf) \
    _Pragma("unroll") for (int kk = 0; kk < 2; ++kk) \
      acc[(MB) * 4 + mf][(NB) * 2 + nf] = __builtin_amdgcn_mfma_f32_16x16x32_bf16( \
          AARR[mf * 2 + kk], BARR[nf * 2 + kk], acc[(MB) * 4 + mf][(NB) * 2 + nf], 0, 0, 0); } while (0)

#define LGKM0SB_() do { asm volatile("s_waitcnt lgkmcnt(0)" ::: "memory"); \
                        __builtin_amdgcn_sched_barrier(0); } while (0)
#define SB_() __builtin_amdgcn_sched_barrier(0)

  // prologue: tile0 {B0,B1,A0,A1} -> buf0 ; tile1 {B0,B1,A0} -> buf1 (A1 staged in ph0)
  STAGE_(0, 1, 0, 0); STAGE_(0, 1, 1, 0); STAGE_(0, 0, 0, 0); STAGE_(0, 0, 1, 0);
  if (NT > 1) {
    STAGE_(1, 1, 0, 64); STAGE_(1, 1, 1, 64); STAGE_(1, 0, 0, 64);
    asm volatile("s_waitcnt vmcnt(6)" ::: "memory");
  } else {
    asm volatile("s_waitcnt vmcnt(0)" ::: "memory");
  }
  __builtin_amdgcn_s_barrier();

  f32x4 acc[8][4] = {};

  for (int t = 0; t < NT; ++t) {
    const int c = t & 1;
    const char* cA = smc + c * 65536 + aRow;
    const char* cB = smc + c * 65536 + bRow;

    // ---- phase 0: read aLo+bLo (12); stage A-h1(t+1) -> other buf; quad LL
    SB_();
    R_ALO(cA); R_BLO(cB);
    if (t + 1 < NT) STAGE_(c ^ 1, 0, 1, (t + 1) << 6);
    asm volatile("s_waitcnt lgkmcnt(8)" ::: "memory");
    __builtin_amdgcn_s_barrier();
    LGKM0SB_();
    __builtin_amdgcn_s_setprio(1);
    QUAD_(aLo, bLo, 0, 0);
    __builtin_amdgcn_s_setprio(0);
    SB_();
    __builtin_amdgcn_s_barrier();

    // ---- phase 1: read bHi (4); quad LH  (B[c] reads complete at end of this phase)
    SB_();
    R_BHI(cB);
    __builtin_amdgcn_s_barrier();
    LGKM0SB_();
    __builtin_amdgcn_s_setprio(1);
    QUAD_(aLo, bHi, 0, 1);
    __builtin_amdgcn_s_setprio(0);
    SB_();
    __builtin_amdgcn_s_barrier();

    // ---- phase 2: read aHi (8); stage B-h0+B-h1(t+2) -> this buf (B reads done); quad HL
    SB_();
    R_AHI(cA);
    if (t + 2 < NT) { STAGE_(c, 1, 0, (t + 2) << 6); STAGE_(c, 1, 1, (t + 2) << 6); }
    __builtin_amdgcn_s_barrier();
    LGKM0SB_();
    __builtin_amdgcn_s_setprio(1);
    QUAD_(aHi, bLo, 1, 0);
    __builtin_amdgcn_s_setprio(0);
    SB_();
    __builtin_amdgcn_s_barrier();

    // ---- phase 3: stage A-h0(t+2) (A reads done); counted vmcnt; quad HH
    SB_();
    if (t + 2 < NT) STAGE_(c, 0, 0, (t + 2) << 6);
    if (t < NT - 2) asm volatile("s_waitcnt vmcnt(6)" ::: "memory");
    else            asm volatile("s_waitcnt vmcnt(0)" ::: "memory");
    __builtin_amdgcn_s_barrier();
    SB_();
    __builtin_amdgcn_s_setprio(1);
    QUAD_(aHi, bHi, 1, 1);
    __builtin_amdgcn_s_setprio(0);
    SB_();
    __builtin_amdgcn_s_barrier();
  }
#undef STAGE_
#undef R_ALO
#undef R_AHI
#undef R_BLO
#undef R_BHI
#undef QUAD_
#undef LGKM0SB_
#undef SB_

  // epilogue
#pragma unroll
  for (int mf = 0; mf < 8; ++mf) {
#pragma unroll
    for (int nf = 0; nf < 4; ++nf) {
      const int col = n0 + wn * 64 + nf * 16 + lr;
      const float bia = bias[col];
#pragma unroll
      for (int r = 0; r < 4; ++r) {
        const int row = m0 + wm * 128 + mf * 16 + lg * 4 + r;
        float v = acc[mf][nf][r] + bia;
        if (EPI == 0) {
          ((u16*)Cout)[(size_t)row * Nn + col] = f2b(v);
        } else if (EPI == 1) {
          v = 0.5f * v * (1.f + erff(v * 0.70710678118654752f));
          ((u16*)Cout)[(size_t)row * Nn + col] = f2b(v);
        } else if (EPI == 2) {
          const int b = row >> 12, j = row & 4095;
          const size_t di = ((size_t)((b << 12) + perm[j])) * 1024 + col;
          ((float*)Cout)[di] = resid[di] + v;
        } else {
          const size_t di = (size_t)row * 1024 + col;
          ((float*)Cout)[di] = resid[di] + v;
        }
      }
    }
  }
}

// ---------------- dilated attention: 1 block per (b, seg, head) ----------------
__global__ __launch_bounds__(256, 2)
void attn_kernel(const u16* __restrict__ qkv, u16* __restrict__ outp) {
  const int blk = blockIdx.x;
  const int h = blk & 15, g = (blk >> 4) & 15, b = blk >> 8;
  const int tid = threadIdx.x, wave = tid >> 6, lane = tid & 63;
  const int lr = lane & 15, lg = lane >> 4;
  const int par = h & 1;

  __shared__ u16 lQ[128 * 64];
  __shared__ u16 lK[128 * 64];
  __shared__ u16 lVt[64 * 128];      // [dh][key]
  __shared__ u16 lP[4][32 * 128];    // per-wave P

  const size_t rbase = (size_t)((b << 12) + (g << 8) + par);

#pragma unroll
  for (int i = 0; i < 4; ++i) {
    const int ou = i * 4096 + wave * 1024;
    const int o = ou + lane * 16;
    const int j = o >> 7, cb = o & 127;
    const u16* gq = qkv + (rbase + 2 * j) * 3072 + h * 64 + (cb >> 1);
    GLDS16(gq, (char*)lQ + ou);
    GLDS16(gq + 1024, (char*)lK + ou);
  }
#pragma unroll
  for (int i = 0; i < 4; ++i) {
    const int c = tid + i * 256;
    const int j = c >> 3, dc = c & 7;
    const uint4 vv = *(const uint4*)(qkv + (rbase + 2 * j) * 3072 + 2048 + h * 64 + dc * 8);
    const u16* pv = (const u16*)&vv;
#pragma unroll
    for (int e = 0; e < 8; ++e) lVt[(dc * 8 + e) * 128 + j] = pv[e];
  }
  __syncthreads();

  f32x4 sacc[2][8] = {};
#pragma unroll
  for (int kk = 0; kk < 2; ++kk) {
    bf16x8 aq[2], bk[8];
#pragma unroll
    for (int mf = 0; mf < 2; ++mf)
      aq[mf] = *(const bf16x8*)&lQ[(wave * 32 + mf * 16 + lr) * 64 + kk * 32 + lg * 8];
#pragma unroll
    for (int nf = 0; nf < 8; ++nf)
      bk[nf] = *(const bf16x8*)&lK[(nf * 16 + lr) * 64 + kk * 32 + lg * 8];
#pragma unroll
    for (int mf = 0; mf < 2; ++mf)
#pragma unroll
      for (int nf = 0; nf < 8; ++nf)
        sacc[mf][nf] = __builtin_amdgcn_mfma_f32_16x16x32_bf16(aq[mf], bk[nf], sacc[mf][nf], 0, 0, 0);
  }

#pragma unroll
  for (int mf = 0; mf < 2; ++mf) {
#pragma unroll
    for (int r = 0; r < 4; ++r) {
      float mx = -3e38f;
#pragma unroll
      for (int nf = 0; nf < 8; ++nf) mx = fmaxf(mx, sacc[mf][nf][r]);
#pragma unroll
      for (int d = 1; d < 16; d <<= 1) mx = fmaxf(mx, __shfl_xor(mx, d));
      float pv[8];
      float sum = 0.f;
#pragma unroll
      for (int nf = 0; nf < 8; ++nf) {
        pv[nf] = __expf((sacc[mf][nf][r] - mx) * 0.125f);
        sum += pv[nf];
      }
#pragma unroll
      for (int d = 1; d < 16; d <<= 1) sum += __shfl_xor(sum, d);
      const float inv = 1.f / sum;
      const int rrow = mf * 16 + lg * 4 + r;
#pragma unroll
      for (int nf = 0; nf < 8; ++nf)
        lP[wave][rrow * 128 + nf * 16 + lr] = f2b(pv[nf] * inv);
    }
  }
  __syncthreads();

  f32x4 oacc[2][4] = {};
#pragma unroll
  for (int kk = 0; kk < 4; ++kk) {
    bf16x8 ap[2], bv[4];
#pragma unroll
    for (int mf = 0; mf < 2; ++mf)
      ap[mf] = *(const bf16x8*)&lP[wave][(mf * 16 + lr) * 128 + kk * 32 + lg * 8];
#pragma unroll
    for (int nf = 0; nf < 4; ++nf)
      bv[nf] = *(const bf16x8*)&lVt[(nf * 16 + lr) * 128 + kk * 32 + lg * 8];
#pragma unroll
    for (int mf = 0; mf < 2; ++mf)
#pragma unroll
      for (int nf = 0; nf < 4; ++nf)
        oacc[mf][nf] = __builtin_amdgcn_mfma_f32_16x16x32_bf16(ap[mf], bv[nf], oacc[mf][nf], 0, 0, 0);
  }

  u16* obase = outp + ((size_t)((b << 12) + (g << 8))) * 1024 + h * 64;
#pragma unroll
  for (int mf = 0; mf < 2; ++mf)
#pragma unroll
    for (int nf = 0; nf < 4; ++nf)
#pragma unroll
      for (int r = 0; r < 4; ++r) {
        const int jq = wave * 32 + mf * 16 + lg * 4 + r;
        obase[(size_t)(par + 2 * jq) * 1024 + nf * 16 + lr] = f2b(oacc[mf][nf][r]);
      }
  const int jz = tid >> 1, hh = (tid & 1) * 32;
  u16* zp = obase + (size_t)((1 - par) + 2 * jz) * 1024 + hh;
  const uint4 z = make_uint4(0u, 0u, 0u, 0u);
#pragma unroll
  for (int i = 0; i < 4; ++i) ((uint4*)zp)[i] = z;
}

// ---------------- launch ----------------
extern "C" void kernel_launch(void* const* d_in, const int* in_sizes, int n_in,
                              void* d_out, int out_size, void* d_ws, size_t ws_size,
                              hipStream_t stream) {
  const float* x    = (const float*)d_in[0];
  const float* ln1g = (const float*)d_in[1];
  const float* ln1b = (const float*)d_in[2];
  const float* wqkv = (const float*)d_in[3];
  const float* bqkv = (const float*)d_in[4];
  const float* wo   = (const float*)d_in[5];
  const float* bo   = (const float*)d_in[6];
  const float* ln2g = (const float*)d_in[7];
  const float* ln2b = (const float*)d_in[8];
  const float* w1   = (const float*)d_in[9];
  const float* b1   = (const float*)d_in[10];
  const float* w2   = (const float*)d_in[11];
  const float* b2   = (const float*)d_in[12];
  const int*   perm = (const int*)d_in[13];
  float* out = (float*)d_out;
  char* ws = (char*)d_ws;

  u16*  r0    = (u16*)ws;                         // 32 MB: xp -> attn_out -> h2
  u16*  qkv   = (u16*)(ws + (32ull << 20));       // 96 MB
  u16*  a1    = (u16*)(ws + (32ull << 20));       // 128 MB (qkv dead by then)
  float* x2   = (float*)(ws + (160ull << 20));    // 64 MB
  u16*  wqkvT = (u16*)(ws + (224ull << 20));      // 6 MB
  u16*  woT   = (u16*)(ws + (230ull << 20));      // 2 MB
  u16*  w1T   = (u16*)(ws + (232ull << 20));      // 8 MB
  u16*  w2T   = (u16*)(ws + (240ull << 20));      // 8 MB

  transpose_bf16<<<dim3(3072 / 32, 1024 / 32), 256, 0, stream>>>(wqkv, wqkvT, 1024, 3072);
  transpose_bf16<<<dim3(1024 / 32, 1024 / 32), 256, 0, stream>>>(wo, woT, 1024, 1024);
  transpose_bf16<<<dim3(4096 / 32, 1024 / 32), 256, 0, stream>>>(w1, w1T, 1024, 4096);
  transpose_bf16<<<dim3(1024 / 32, 4096 / 32), 256, 0, stream>>>(w2, w2T, 4096, 1024);

  ln_rows<<<16384, 256, 0, stream>>>(x, ln1g, ln1b, perm, r0);                  // xp = LN1(x)[perm]
  gemm256<0><<<(16384 / 256) * (3072 / 256), 512, 0, stream>>>(r0, wqkvT, bqkv, qkv, nullptr, nullptr,
                                                               16384, 3072, 1024);
  attn_kernel<<<1024, 256, 0, stream>>>(qkv, r0);                               // attn_out
  gemm256<2><<<(16384 / 256) * (1024 / 256), 512, 0, stream>>>(r0, woT, bo, x2, x, perm,
                                                               16384, 1024, 1024);
  ln_rows<<<16384, 256, 0, stream>>>(x2, ln2g, ln2b, nullptr, r0);              // h2 = LN2(x2)
  gemm256<1><<<(16384 / 256) * (4096 / 256), 512, 0, stream>>>(r0, w1T, b1, a1, nullptr, nullptr,
                                                               16384, 4096, 1024);
  gemm256<3><<<(16384 / 256) * (1024 / 256), 512, 0, stream>>>(a1, w2T, b2, out, x2, nullptr,
                                                               16384, 1024, 4096);
}

// Round 8
// 604.636 us; speedup vs baseline: 1.7870x; 1.0212x over previous
//
#include <hip/hip_runtime.h>

typedef short bf16x8 __attribute__((ext_vector_type(8)));
typedef float f32x4 __attribute__((ext_vector_type(4)));
typedef unsigned short u16;

#define GLDS16(g, l) __builtin_amdgcn_global_load_lds( \
    (const __attribute__((address_space(1))) void*)(g), \
    (__attribute__((address_space(3))) void*)(l), 16, 0, 0)

// opaque-to-legalizer LDS read: no compiler-inserted vmcnt(0) ordering vs LDS-DMA
#define DSR_(dst, p) asm volatile("ds_read_b128 %0, %1" \
    : "=v"(dst) : "v"((const __attribute__((address_space(3))) void*)(p)))

__device__ __forceinline__ u16 f2b(float f) {
  unsigned u = __float_as_uint(f);
  u += 0x7fffu + ((u >> 16) & 1u);
  return (u16)(u >> 16);
}

// ---------------- weight transpose + bf16 convert: w[K][N] -> wt[N][K] ----------------
__global__ __launch_bounds__(256)
void transpose_bf16(const float* __restrict__ w, u16* __restrict__ wt, int K, int N) {
  __shared__ float tile[32][33];
  const int n0 = blockIdx.x * 32, k0 = blockIdx.y * 32;
  const int tx = threadIdx.x & 31, ty = threadIdx.x >> 5;   // 32 x 8
#pragma unroll
  for (int i = 0; i < 4; ++i)
    tile[ty + i * 8][tx] = w[(size_t)(k0 + ty + i * 8) * N + n0 + tx];
  __syncthreads();
#pragma unroll
  for (int i = 0; i < 4; ++i)
    wt[(size_t)(n0 + ty + i * 8) * K + k0 + tx] = f2b(tile[tx][ty + i * 8]);
}

// ---------------- layernorm (optional gather-permute) -> bf16 row ----------------
__global__ __launch_bounds__(256)
void ln_rows(const float* __restrict__ src, const float* __restrict__ gam,
             const float* __restrict__ bet, const int* __restrict__ perm,
             u16* __restrict__ dst) {
  const int orow = blockIdx.x;                 // output row, 0..16383
  const int b = orow >> 12, j = orow & 4095;
  const int srow = perm ? ((b << 12) + perm[j]) : orow;
  const float4 v = ((const float4*)(src + (size_t)srow * 1024))[threadIdx.x];
  float s = v.x + v.y + v.z + v.w;
  float s2 = v.x * v.x + v.y * v.y + v.z * v.z + v.w * v.w;
#pragma unroll
  for (int d = 1; d < 64; d <<= 1) { s += __shfl_xor(s, d); s2 += __shfl_xor(s2, d); }
  __shared__ float rs[4], rs2[4];
  const int wave = threadIdx.x >> 6, lane = threadIdx.x & 63;
  if (lane == 0) { rs[wave] = s; rs2[wave] = s2; }
  __syncthreads();
  s = rs[0] + rs[1] + rs[2] + rs[3];
  s2 = rs2[0] + rs2[1] + rs2[2] + rs2[3];
  const float mu = s * (1.f / 1024.f);
  const float var = s2 * (1.f / 1024.f) - mu * mu;
  const float rstd = rsqrtf(var + 1e-5f);
  const int c = threadIdx.x * 4;
  const float4 gg = *(const float4*)(gam + c);
  const float4 bb = *(const float4*)(bet + c);
  const u16 o0 = f2b((v.x - mu) * rstd * gg.x + bb.x);
  const u16 o1 = f2b((v.y - mu) * rstd * gg.y + bb.y);
  const u16 o2 = f2b((v.z - mu) * rstd * gg.z + bb.z);
  const u16 o3 = f2b((v.w - mu) * rstd * gg.w + bb.w);
  const unsigned lo = (unsigned)o0 | ((unsigned)o1 << 16);
  const unsigned hi = (unsigned)o2 | ((unsigned)o3 << 16);
  *(uint2*)(dst + (size_t)orow * 1024 + c) = make_uint2(lo, hi);
}

// ---------------- 256x256 GEMM, 8-phase, L2-locality 2D raster per XCD ----------------
// Tile mapping: XCD x = wg&7 owns m-band [8x, 8x+8); locals enumerate 8m x 4n groups
// (nn fastest) so the 32 co-resident blocks per XCD share A k-tiles (4x) and B k-tiles
// (8x) inside a ~1 MB temporal window -> staging served from L2, not L3/HBM.
// Requires M==16384 (64 m-tiles) and (Nn>>8)%4==0 — true for all call sites.
// EPI 0: bf16 store; 1: GELU+bf16; 2: perm-scatter + resid, fp32; 3: resid, fp32
template <int EPI>
__global__ __launch_bounds__(512, 2)
void gemm256(const u16* __restrict__ A, const u16* __restrict__ Bt,
             const float* __restrict__ bias, void* __restrict__ Cout,
             const float* __restrict__ resid, const int* __restrict__ perm,
             int M, int Nn, int K) {
  __shared__ u16 sm[65536];                 // 128 KiB: [buf0|buf1], each {A 32K, B 32K}
  char* const smc = (char*)sm;
  const int tid = threadIdx.x;
  const int w = tid >> 6, lane = tid & 63;
  const int lr = lane & 15, lg = lane >> 4;
  const int wm = w >> 2, wn = w & 3;

  // XCD-band 2D raster (bijective: 8 xcd * 8 mm * 4 nn * (gy/4) ng = 64*gy tiles)
  const int wg = blockIdx.x;
  const int x = wg & 7, l = wg >> 3;
  const int mm = (l >> 2) & 7, nn = l & 3, ng = l >> 5;
  const int m0 = ((x << 3) + mm) << 8;
  const int n0 = ((ng << 2) + nn) << 8;

  // staging: LDS written linearly by global_load_lds; global source pre-swizzled
  // so ds_read with (col ^ ((row&7)<<4)) is correct.
  const int srow = tid >> 3;                                   // 0..63
  const int scol = ((tid & 7) ^ (srow & 7)) << 3;              // element col
  const size_t aSrc = (size_t)(m0 + srow) * K + scol;
  const size_t bSrc = (size_t)(n0 + srow) * K + scol;
  char* const lWav = smc + w * 1024;

  // read-side constants
  const int slot0 = (lg ^ (lr & 7)) << 4;                      // swizzled 16B slot
  const int aRow = (wm * 128 + lr) * 128;
  const int bRow = (wn * 64 + lr) * 128 + 32768;

  const int NT = K >> 6;

#define STAGE_(d, mat, h, k0) do { \
    const u16* gp = ((mat) ? Bt : A) + ((mat) ? bSrc : aSrc) + (size_t)(h) * 128 * K + (k0); \
    char* lp = lWav + (d) * 65536 + (mat) * 32768 + (h) * 16384; \
    GLDS16(gp, lp); GLDS16(gp + (size_t)64 * K, lp + 8192); } while (0)

  // fragment registers (consumed same-phase, after explicit lgkmcnt(0))
  bf16x8 aLo[8], aHi[8], bLo[4], bHi[4];

#define R_ALO(P) do { _Pragma("unroll") for (int mf = 0; mf < 4; ++mf) \
    _Pragma("unroll") for (int kk = 0; kk < 2; ++kk) \
      DSR_(aLo[mf * 2 + kk], (P) + mf * 2048 + (slot0 ^ (kk << 6))); } while (0)
#define R_AHI(P) do { _Pragma("unroll") for (int mf = 0; mf < 4; ++mf) \
    _Pragma("unroll") for (int kk = 0; kk < 2; ++kk) \
      DSR_(aHi[mf * 2 + kk], (P) + (4 + mf) * 2048 + (slot0 ^ (kk << 6))); } while (0)
#define R_BLO(P) do { _Pragma("unroll") for (int nf = 0; nf < 2; ++nf) \
    _Pragma("unroll") for (int kk = 0; kk < 2; ++kk) \
      DSR_(bLo[nf * 2 + kk], (P) + nf * 2048 + (slot0 ^ (kk << 6))); } while (0)
#define R_BHI(P) do { _Pragma("unroll") for (int nf = 0; nf < 2; ++nf) \
    _Pragma("unroll") for (int kk = 0; kk < 2; ++kk) \
      DSR_(bHi[nf * 2 + kk], (P) + (2 + nf) * 2048 + (slot0 ^ (kk << 6))); } while (0)

#define QUAD_(AARR, BARR, MB, NB) do { _Pragma("unroll") for (int mf = 0; mf < 4; ++mf) \
    _Pragma("unroll") for (int nf = 0; nf < 2; ++nf) \
    _Pragma("unroll") for (int kk = 0; kk < 2; ++kk) \
      acc[(MB) * 4 + mf][(NB) * 2 + nf] = __builtin_amdgcn_mfma_f32_16x16x32_bf16( \
          AARR[mf * 2 + kk], BARR[nf * 2 + kk], acc[(MB) * 4 + mf][(NB) * 2 + nf], 0, 0, 0); } while (0)

#define LGKM0SB_() do { asm volatile("s_waitcnt lgkmcnt(0)" ::: "memory"); \
                        __builtin_amdgcn_sched_barrier(0); } while (0)
#define SB_() __builtin_amdgcn_sched_barrier(0)

  // prologue: tile0 {B0,B1,A0,A1} -> buf0 ; tile1 {B0,B1,A0} -> buf1 (A1 staged in ph0)
  STAGE_(0, 1, 0, 0); STAGE_(0, 1, 1, 0); STAGE_(0, 0, 0, 0); STAGE_(0, 0, 1, 0);
  if (NT > 1) {
    STAGE_(1, 1, 0, 64); STAGE_(1, 1, 1, 64); STAGE_(1, 0, 0, 64);
    asm volatile("s_waitcnt vmcnt(6)" ::: "memory");
  } else {
    asm volatile("s_waitcnt vmcnt(0)" ::: "memory");
  }
  __builtin_amdgcn_s_barrier();

  f32x4 acc[8][4] = {};

  for (int t = 0; t < NT; ++t) {
    const int c = t & 1;
    const char* cA = smc + c * 65536 + aRow;
    const char* cB = smc + c * 65536 + bRow;

    // ---- phase 0: read aLo+bLo (12); stage A-h1(t+1) -> other buf; quad LL
    SB_();
    R_ALO(cA); R_BLO(cB);
    if (t + 1 < NT) STAGE_(c ^ 1, 0, 1, (t + 1) << 6);
    asm volatile("s_waitcnt lgkmcnt(8)" ::: "memory");
    __builtin_amdgcn_s_barrier();
    LGKM0SB_();
    __builtin_amdgcn_s_setprio(1);
    QUAD_(aLo, bLo, 0, 0);
    __builtin_amdgcn_s_setprio(0);
    SB_();
    __builtin_amdgcn_s_barrier();

    // ---- phase 1: read bHi (4); quad LH  (B[c] reads complete at end of this phase)
    SB_();
    R_BHI(cB);
    __builtin_amdgcn_s_barrier();
    LGKM0SB_();
    __builtin_amdgcn_s_setprio(1);
    QUAD_(aLo, bHi, 0, 1);
    __builtin_amdgcn_s_setprio(0);
    SB_();
    __builtin_amdgcn_s_barrier();

    // ---- phase 2: read aHi (8); stage B-h0+B-h1(t+2) -> this buf (B reads done); quad HL
    SB_();
    R_AHI(cA);
    if (t + 2 < NT) { STAGE_(c, 1, 0, (t + 2) << 6); STAGE_(c, 1, 1, (t + 2) << 6); }
    __builtin_amdgcn_s_barrier();
    LGKM0SB_();
    __builtin_amdgcn_s_setprio(1);
    QUAD_(aHi, bLo, 1, 0);
    __builtin_amdgcn_s_setprio(0);
    SB_();
    __builtin_amdgcn_s_barrier();

    // ---- phase 3: stage A-h0(t+2) (A reads done); counted vmcnt; quad HH
    SB_();
    if (t + 2 < NT) STAGE_(c, 0, 0, (t + 2) << 6);
    if (t < NT - 2) asm volatile("s_waitcnt vmcnt(6)" ::: "memory");
    else            asm volatile("s_waitcnt vmcnt(0)" ::: "memory");
    __builtin_amdgcn_s_barrier();
    SB_();
    __builtin_amdgcn_s_setprio(1);
    QUAD_(aHi, bHi, 1, 1);
    __builtin_amdgcn_s_setprio(0);
    SB_();
    __builtin_amdgcn_s_barrier();
  }
#undef STAGE_
#undef R_ALO
#undef R_AHI
#undef R_BLO
#undef R_BHI
#undef QUAD_
#undef LGKM0SB_
#undef SB_

  // epilogue
#pragma unroll
  for (int mf = 0; mf < 8; ++mf) {
#pragma unroll
    for (int nf = 0; nf < 4; ++nf) {
      const int col = n0 + wn * 64 + nf * 16 + lr;
      const float bia = bias[col];
#pragma unroll
      for (int r = 0; r < 4; ++r) {
        const int row = m0 + wm * 128 + mf * 16 + lg * 4 + r;
        float v = acc[mf][nf][r] + bia;
        if (EPI == 0) {
          ((u16*)Cout)[(size_t)row * Nn + col] = f2b(v);
        } else if (EPI == 1) {
          v = 0.5f * v * (1.f + erff(v * 0.70710678118654752f));
          ((u16*)Cout)[(size_t)row * Nn + col] = f2b(v);
        } else if (EPI == 2) {
          const int b = row >> 12, j = row & 4095;
          const size_t di = ((size_t)((b << 12) + perm[j])) * 1024 + col;
          ((float*)Cout)[di] = resid[di] + v;
        } else {
          const size_t di = (size_t)row * 1024 + col;
          ((float*)Cout)[di] = resid[di] + v;
        }
      }
    }
  }
}

// ---------------- dilated attention: 1 block per (b, seg, head) ----------------
__global__ __launch_bounds__(256, 2)
void attn_kernel(const u16* __restrict__ qkv, u16* __restrict__ outp) {
  const int blk = blockIdx.x;
  const int h = blk & 15, g = (blk >> 4) & 15, b = blk >> 8;
  const int tid = threadIdx.x, wave = tid >> 6, lane = tid & 63;
  const int lr = lane & 15, lg = lane >> 4;
  const int par = h & 1;

  __shared__ u16 lQ[128 * 64];
  __shared__ u16 lK[128 * 64];
  __shared__ u16 lVt[64 * 128];      // [dh][key]
  __shared__ u16 lP[4][32 * 128];    // per-wave P

  const size_t rbase = (size_t)((b << 12) + (g << 8) + par);

#pragma unroll
  for (int i = 0; i < 4; ++i) {
    const int ou = i * 4096 + wave * 1024;
    const int o = ou + lane * 16;
    const int j = o >> 7, cb = o & 127;
    const u16* gq = qkv + (rbase + 2 * j) * 3072 + h * 64 + (cb >> 1);
    GLDS16(gq, (char*)lQ + ou);
    GLDS16(gq + 1024, (char*)lK + ou);
  }
#pragma unroll
  for (int i = 0; i < 4; ++i) {
    const int c = tid + i * 256;
    const int j = c >> 3, dc = c & 7;
    const uint4 vv = *(const uint4*)(qkv + (rbase + 2 * j) * 3072 + 2048 + h * 64 + dc * 8);
    const u16* pv = (const u16*)&vv;
#pragma unroll
    for (int e = 0; e < 8; ++e) lVt[(dc * 8 + e) * 128 + j] = pv[e];
  }
  __syncthreads();

  f32x4 sacc[2][8] = {};
#pragma unroll
  for (int kk = 0; kk < 2; ++kk) {
    bf16x8 aq[2], bk[8];
#pragma unroll
    for (int mf = 0; mf < 2; ++mf)
      aq[mf] = *(const bf16x8*)&lQ[(wave * 32 + mf * 16 + lr) * 64 + kk * 32 + lg * 8];
#pragma unroll
    for (int nf = 0; nf < 8; ++nf)
      bk[nf] = *(const bf16x8*)&lK[(nf * 16 + lr) * 64 + kk * 32 + lg * 8];
#pragma unroll
    for (int mf = 0; mf < 2; ++mf)
#pragma unroll
      for (int nf = 0; nf < 8; ++nf)
        sacc[mf][nf] = __builtin_amdgcn_mfma_f32_16x16x32_bf16(aq[mf], bk[nf], sacc[mf][nf], 0, 0, 0);
  }

#pragma unroll
  for (int mf = 0; mf < 2; ++mf) {
#pragma unroll
    for (int r = 0; r < 4; ++r) {
      float mx = -3e38f;
#pragma unroll
      for (int nf = 0; nf < 8; ++nf) mx = fmaxf(mx, sacc[mf][nf][r]);
#pragma unroll
      for (int d = 1; d < 16; d <<= 1) mx = fmaxf(mx, __shfl_xor(mx, d));
      float pv[8];
      float sum = 0.f;
#pragma unroll
      for (int nf = 0; nf < 8; ++nf) {
        pv[nf] = __expf((sacc[mf][nf][r] - mx) * 0.125f);
        sum += pv[nf];
      }
#pragma unroll
      for (int d = 1; d < 16; d <<= 1) sum += __shfl_xor(sum, d);
      const float inv = 1.f / sum;
      const int rrow = mf * 16 + lg * 4 + r;
#pragma unroll
      for (int nf = 0; nf < 8; ++nf)
        lP[wave][rrow * 128 + nf * 16 + lr] = f2b(pv[nf] * inv);
    }
  }
  __syncthreads();

  f32x4 oacc[2][4] = {};
#pragma unroll
  for (int kk = 0; kk < 4; ++kk) {
    bf16x8 ap[2], bv[4];
#pragma unroll
    for (int mf = 0; mf < 2; ++mf)
      ap[mf] = *(const bf16x8*)&lP[wave][(mf * 16 + lr) * 128 + kk * 32 + lg * 8];
#pragma unroll
    for (int nf = 0; nf < 4; ++nf)
      bv[nf] = *(const bf16x8*)&lVt[(nf * 16 + lr) * 128 + kk * 32 + lg * 8];
#pragma unroll
    for (int mf = 0; mf < 2; ++mf)
#pragma unroll
      for (int nf = 0; nf < 4; ++nf)
        oacc[mf][nf] = __builtin_amdgcn_mfma_f32_16x16x32_bf16(ap[mf], bv[nf], oacc[mf][nf], 0, 0, 0);
  }

  u16* obase = outp + ((size_t)((b << 12) + (g << 8))) * 1024 + h * 64;
#pragma unroll
  for (int mf = 0; mf < 2; ++mf)
#pragma unroll
    for (int nf = 0; nf < 4; ++nf)
#pragma unroll
      for (int r = 0; r < 4; ++r) {
        const int jq = wave * 32 + mf * 16 + lg * 4 + r;
        obase[(size_t)(par + 2 * jq) * 1024 + nf * 16 + lr] = f2b(oacc[mf][nf][r]);
      }
  const int jz = tid >> 1, hh = (tid & 1) * 32;
  u16* zp = obase + (size_t)((1 - par) + 2 * jz) * 1024 + hh;
  const uint4 z = make_uint4(0u, 0u, 0u, 0u);
#pragma unroll
  for (int i = 0; i < 4; ++i) ((uint4*)zp)[i] = z;
}

// ---------------- launch ----------------
extern "C" void kernel_launch(void* const* d_in, const int* in_sizes, int n_in,
                              void* d_out, int out_size, void* d_ws, size_t ws_size,
                              hipStream_t stream) {
  const float* x    = (const float*)d_in[0];
  const float* ln1g = (const float*)d_in[1];
  const float* ln1b = (const float*)d_in[2];
  const float* wqkv = (const float*)d_in[3];
  const float* bqkv = (const float*)d_in[4];
  const float* wo   = (const float*)d_in[5];
  const float* bo   = (const float*)d_in[6];
  const float* ln2g = (const float*)d_in[7];
  const float* ln2b = (const float*)d_in[8];
  const float* w1   = (const float*)d_in[9];
  const float* b1   = (const float*)d_in[10];
  const float* w2   = (const float*)d_in[11];
  const float* b2   = (const float*)d_in[12];
  const int*   perm = (const int*)d_in[13];
  float* out = (float*)d_out;
  char* ws = (char*)d_ws;

  u16*  r0    = (u16*)ws;                         // 32 MB: xp -> attn_out -> h2
  u16*  qkv   = (u16*)(ws + (32ull << 20));       // 96 MB
  u16*  a1    = (u16*)(ws + (32ull << 20));       // 128 MB (qkv dead by then)
  float* x2   = (float*)(ws + (160ull << 20));    // 64 MB
  u16*  wqkvT = (u16*)(ws + (224ull << 20));      // 6 MB
  u16*  woT   = (u16*)(ws + (230ull << 20));      // 2 MB
  u16*  w1T   = (u16*)(ws + (232ull << 20));      // 8 MB
  u16*  w2T   = (u16*)(ws + (240ull << 20));      // 8 MB

  transpose_bf16<<<dim3(3072 / 32, 1024 / 32), 256, 0, stream>>>(wqkv, wqkvT, 1024, 3072);
  transpose_bf16<<<dim3(1024 / 32, 1024 / 32), 256, 0, stream>>>(wo, woT, 1024, 1024);
  transpose_bf16<<<dim3(4096 / 32, 1024 / 32), 256, 0, stream>>>(w1, w1T, 1024, 4096);
  transpose_bf16<<<dim3(1024 / 32, 4096 / 32), 256, 0, stream>>>(w2, w2T, 4096, 1024);

  ln_rows<<<16384, 256, 0, stream>>>(x, ln1g, ln1b, perm, r0);                  // xp = LN1(x)[perm]
  gemm256<0><<<(16384 / 256) * (3072 / 256), 512, 0, stream>>>(r0, wqkvT, bqkv, qkv, nullptr, nullptr,
                                                               16384, 3072, 1024);
  attn_kernel<<<1024, 256, 0, stream>>>(qkv, r0);                               // attn_out
  gemm256<2><<<(16384 / 256) * (1024 / 256), 512, 0, stream>>>(r0, woT, bo, x2, x, perm,
                                                               16384, 1024, 1024);
  ln_rows<<<16384, 256, 0, stream>>>(x2, ln2g, ln2b, nullptr, r0);              // h2 = LN2(x2)
  gemm256<1><<<(16384 / 256) * (4096 / 256), 512, 0, stream>>>(r0, w1T, b1, a1, nullptr, nullptr,
                                                               16384, 4096, 1024);
  gemm256<3><<<(16384 / 256) * (1024 / 256), 512, 0, stream>>>(a1, w2T, b2, out, x2, nullptr,
                                                               16384, 1024, 4096);
}